// Round 1
// baseline (349.841 us; speedup 1.0000x reference)
//
#include <hip/hip_runtime.h>

// FactorizedSpectralConv: B=8, S1=S2=256, C=64, M1=M2=32.
// Fully-fused per-dim kernels: truncated DFT -> complex channel mix -> iDFT.
// fp32 vector-FMA implementation (round 0).

namespace {

constexpr int Bn = 8, S = 256, C = 64, M = 32, MC = 64;  // MC = 2*M mode-components

// ws layout (float offsets)
constexpr int OFF_FWDT = 0;                 // fwdT[x][mc]   : [256][64]
constexpr int OFF_INVT = 16384;             // invTT[mc][x]  : [64][256]
constexpr int OFF_KT0  = 32768;             // kT0[r][j][i][{R,I}] : 32*64*64*2
constexpr int OFF_KT1  = 32768 + 262144;    // kT1 same
// total 557056 floats = 2.23 MB

__device__ inline void fma4(float4& a, float s, const float4& v) {
  a.x += s * v.x; a.y += s * v.y; a.z += s * v.z; a.w += s * v.w;
}
__device__ inline void add4(float4& a, const float4& v) {
  a.x += v.x; a.y += v.y; a.z += v.z; a.w += v.w;
}

// fwdT[x][2r]   =  cos(2*pi*r*x/256)/256      (rfft norm="forward": real part coeff)
// fwdT[x][2r+1] = -sin(2*pi*r*x/256)/256      (imag part coeff)
// invTT[2r][x]  =  w_r*cos(2*pi*r*x/256)      (irfft norm="forward", w_0=1, w_r=2)
// invTT[2r+1][x]= -w_r*sin(2*pi*r*x/256)
__global__ void k_init_tables(float* __restrict__ ws) {
  int t = blockIdx.x * 256 + threadIdx.x;   // 0..16383
  int x = t >> 6, mc = t & 63;
  int r = mc >> 1, im = mc & 1;
  double ang = (double)((r * x) & 255) * (3.14159265358979323846 / 128.0);
  float s = (float)sin(ang), c = (float)cos(ang);
  ws[OFF_FWDT + t] = im ? (-s * (1.0f / 256.0f)) : (c * (1.0f / 256.0f));
  float w = (r == 0) ? 1.0f : 2.0f;
  ws[OFF_INVT + mc * 256 + x] = im ? (-w * s) : (w * c);
}

// kT[(r*64+j)*64 + i][{R,I}] = { kr[r][i][j], ki[r][i][j] }
__global__ void k_init_kT(const float* __restrict__ kr, const float* __restrict__ ki,
                          float* __restrict__ kT) {
  int t = blockIdx.x * 256 + threadIdx.x;   // 0..131071 ; t = (r*64 + j)*64 + i
  int r = t >> 12, j = (t >> 6) & 63, i = t & 63;
  int src = (r * 64 + i) * 64 + j;
  kT[2 * t + 0] = kr[src];
  kT[2 * t + 1] = ki[src];
}

// One block = (b, 4 consecutive slabs along the NON-transformed spatial axis).
// DIM==0: transform along x (axis -3); slabs are y. DIM==1: along y; slabs are x.
// Phases: 1) DFT (acc in regs)  2) dump Xf to LDS  3) complex mix (in place)
//         4) iDFT -> global (DIM0: store, DIM1: accumulate).
template <int DIM>
__launch_bounds__(256)
__global__ void k_dim(const float* __restrict__ X, const float* __restrict__ ws,
                      float* __restrict__ out) {
  __shared__ float sm[16384];               // 64 KB
  float* Xc = sm;                           // phase 1: [32][256] chunk
  float* Ft = sm + 8192;                    // phase 1: [32][64]
  float* XY = sm;                           // phases 2-4: [4][64][64] Xf/Yt slabs

  const int tid = threadIdx.x;
  const int b   = blockIdx.x >> 6;
  const int t4  = (blockIdx.x & 63) * 4;    // first slab index
  const float* fwdT = ws + OFF_FWDT;
  const float* invT = ws + OFF_INVT;
  const float* kT   = ws + (DIM == 0 ? OFF_KT0 : OFF_KT1);
  const size_t bbase = (size_t)b * (S * S * C);

  // ---------------- Phase 1: truncated DFT ----------------
  // acc[m] holds Xf[mc = rg*16+m][cols 4cg..4cg+3], cols = (slab p = cg>>4, j = (cg&15)*4+cc)
  const int rg = tid >> 6;                  // 0..3  (mode-comp group, wave-uniform)
  const int cg = tid & 63;                  // 0..63 (column group)
  float4 acc[16];
#pragma unroll
  for (int m = 0; m < 16; ++m) acc[m] = make_float4(0.f, 0.f, 0.f, 0.f);

  for (int ch = 0; ch < 8; ++ch) {
    const int u0 = ch * 32;                 // contraction base (x for DIM0, y for DIM1)
    // stage X chunk: Xc[uu][c], c = slab*64 + j
#pragma unroll
    for (int it = 0; it < 8; ++it) {
      int flat = it * 1024 + tid * 4;
      int uu = flat >> 8, c = flat & 255;
      size_t g;
      if (DIM == 0)
        g = bbase + (size_t)(u0 + uu) * (S * C) + (size_t)t4 * C + c;
      else
        g = bbase + (size_t)(t4 + (c >> 6)) * (S * C) + (size_t)(u0 + uu) * C + (c & 63);
      *(float4*)&Xc[uu * 256 + c] = *(const float4*)&X[g];
    }
    // stage twiddle chunk: Ft[uu][mc]
#pragma unroll
    for (int it = 0; it < 2; ++it) {
      int flat = it * 1024 + tid * 4;
      *(float4*)&Ft[flat] = *(const float4*)&fwdT[u0 * 64 + flat];
    }
    __syncthreads();
#pragma unroll 4
    for (int uu = 0; uu < 32; ++uu) {
      float4 v  = *(float4*)&Xc[uu * 256 + cg * 4];
      float4 t0 = *(float4*)&Ft[uu * 64 + rg * 16 + 0];
      float4 t1 = *(float4*)&Ft[uu * 64 + rg * 16 + 4];
      float4 t2 = *(float4*)&Ft[uu * 64 + rg * 16 + 8];
      float4 t3 = *(float4*)&Ft[uu * 64 + rg * 16 + 12];
      fma4(acc[0],  t0.x, v); fma4(acc[1],  t0.y, v);
      fma4(acc[2],  t0.z, v); fma4(acc[3],  t0.w, v);
      fma4(acc[4],  t1.x, v); fma4(acc[5],  t1.y, v);
      fma4(acc[6],  t1.z, v); fma4(acc[7],  t1.w, v);
      fma4(acc[8],  t2.x, v); fma4(acc[9],  t2.y, v);
      fma4(acc[10], t2.z, v); fma4(acc[11], t2.w, v);
      fma4(acc[12], t3.x, v); fma4(acc[13], t3.y, v);
      fma4(acc[14], t3.z, v); fma4(acc[15], t3.w, v);
    }
    __syncthreads();
  }

  // ---------------- Phase 2: Xf -> LDS ----------------
  {
    const int p  = cg >> 4;
    const int j0 = (cg & 15) * 4;
#pragma unroll
    for (int m = 0; m < 16; ++m)
      *(float4*)&XY[(p * 64 + rg * 16 + m) * 64 + j0] = acc[m];
  }
  __syncthreads();

  // ---------------- Phase 3: complex channel mix (in place) ----------------
  // thread: mode r = tid>>3, out-channel group ig = tid&7 (i = 8*ig..8*ig+7)
  {
    const int r  = tid >> 3;
    const int ig = tid & 7;
    float yR[4][8], yI[4][8];
#pragma unroll
    for (int p = 0; p < 4; ++p)
#pragma unroll
      for (int q = 0; q < 8; ++q) { yR[p][q] = 0.f; yI[p][q] = 0.f; }

    const float4* kp = (const float4*)(kT + (size_t)r * 8192 + ig * 16);
#pragma unroll 2
    for (int j = 0; j < 64; ++j) {
      float4 ka = kp[j * 32 + 0];   // (R,I) for i0,i1
      float4 kb = kp[j * 32 + 1];   // i2,i3
      float4 kc = kp[j * 32 + 2];   // i4,i5
      float4 kd = kp[j * 32 + 3];   // i6,i7
      float xr[4], xi[4];
#pragma unroll
      for (int p = 0; p < 4; ++p) {
        xr[p] = XY[(p * 64 + 2 * r) * 64 + j];
        xi[p] = XY[(p * 64 + 2 * r + 1) * 64 + j];
      }
#pragma unroll
      for (int p = 0; p < 4; ++p) {
        float ar = xr[p], ai = xi[p];
        yR[p][0] += ka.x * ar - ka.y * ai;  yI[p][0] += ka.x * ai + ka.y * ar;
        yR[p][1] += ka.z * ar - ka.w * ai;  yI[p][1] += ka.z * ai + ka.w * ar;
        yR[p][2] += kb.x * ar - kb.y * ai;  yI[p][2] += kb.x * ai + kb.y * ar;
        yR[p][3] += kb.z * ar - kb.w * ai;  yI[p][3] += kb.z * ai + kb.w * ar;
        yR[p][4] += kc.x * ar - kc.y * ai;  yI[p][4] += kc.x * ai + kc.y * ar;
        yR[p][5] += kc.z * ar - kc.w * ai;  yI[p][5] += kc.z * ai + kc.w * ar;
        yR[p][6] += kd.x * ar - kd.y * ai;  yI[p][6] += kd.x * ai + kd.y * ar;
        yR[p][7] += kd.z * ar - kd.w * ai;  yI[p][7] += kd.z * ai + kd.w * ar;
      }
    }
    __syncthreads();
#pragma unroll
    for (int p = 0; p < 4; ++p) {
      float* rowR = &XY[(p * 64 + 2 * r) * 64 + ig * 8];
      float* rowI = &XY[(p * 64 + 2 * r + 1) * 64 + ig * 8];
      *(float4*)&rowR[0] = make_float4(yR[p][0], yR[p][1], yR[p][2], yR[p][3]);
      *(float4*)&rowR[4] = make_float4(yR[p][4], yR[p][5], yR[p][6], yR[p][7]);
      *(float4*)&rowI[0] = make_float4(yI[p][0], yI[p][1], yI[p][2], yI[p][3]);
      *(float4*)&rowI[4] = make_float4(yI[p][4], yI[p][5], yI[p][6], yI[p][7]);
    }
    __syncthreads();
  }

  // ---------------- Phase 4: iDFT -> global ----------------
  // thread: xg = tid>>5 (8 groups of 8 output positions), ng = tid&31 -> (slab p4, col c0..c0+7)
  {
    const int xg = tid >> 5;
    const int ng = tid & 31;
    const int p4 = ng >> 3;
    const int c0 = (ng & 7) * 8;
    const float* XYp = &XY[(p4 * 64) * 64 + c0];
    for (int seg = 0; seg < 4; ++seg) {
      float4 a0[8], a1[8];
#pragma unroll
      for (int q = 0; q < 8; ++q) {
        a0[q] = make_float4(0.f, 0.f, 0.f, 0.f);
        a1[q] = make_float4(0.f, 0.f, 0.f, 0.f);
      }
      const int ub = seg * 64 + xg * 8;     // output position base (x for DIM0, y for DIM1)
#pragma unroll 4
      for (int k = 0; k < 64; ++k) {
        const float* twp = invT + k * 256 + ub;
        float4 t0 = *(const float4*)&twp[0];
        float4 t1 = *(const float4*)&twp[4];
        float4 y0 = *(float4*)&XYp[k * 64];
        float4 y1 = *(float4*)&XYp[k * 64 + 4];
        fma4(a0[0], t0.x, y0); fma4(a1[0], t0.x, y1);
        fma4(a0[1], t0.y, y0); fma4(a1[1], t0.y, y1);
        fma4(a0[2], t0.z, y0); fma4(a1[2], t0.z, y1);
        fma4(a0[3], t0.w, y0); fma4(a1[3], t0.w, y1);
        fma4(a0[4], t1.x, y0); fma4(a1[4], t1.x, y1);
        fma4(a0[5], t1.y, y0); fma4(a1[5], t1.y, y1);
        fma4(a0[6], t1.z, y0); fma4(a1[6], t1.z, y1);
        fma4(a0[7], t1.w, y0); fma4(a1[7], t1.w, y1);
      }
#pragma unroll
      for (int q = 0; q < 8; ++q) {
        int u = ub + q;
        size_t g;
        if (DIM == 0)
          g = bbase + (size_t)u * (S * C) + (size_t)(t4 + p4) * C + c0;
        else
          g = bbase + (size_t)(t4 + p4) * (S * C) + (size_t)u * C + c0;
        if (DIM == 0) {
          *(float4*)&out[g]     = a0[q];
          *(float4*)&out[g + 4] = a1[q];
        } else {
          float4 o0 = *(const float4*)&out[g];
          float4 o1 = *(const float4*)&out[g + 4];
          add4(o0, a0[q]); add4(o1, a1[q]);
          *(float4*)&out[g]     = o0;
          *(float4*)&out[g + 4] = o1;
        }
      }
    }
  }
}

}  // namespace

extern "C" void kernel_launch(void* const* d_in, const int* in_sizes, int n_in,
                              void* d_out, int out_size, void* d_ws, size_t ws_size,
                              hipStream_t stream) {
  (void)in_sizes; (void)n_in; (void)out_size; (void)ws_size;
  const float* X   = (const float*)d_in[0];
  const float* k0r = (const float*)d_in[1];
  const float* k0i = (const float*)d_in[2];
  const float* k1r = (const float*)d_in[3];
  const float* k1i = (const float*)d_in[4];
  float* out = (float*)d_out;
  float* ws  = (float*)d_ws;

  k_init_tables<<<64, 256, 0, stream>>>(ws);
  k_init_kT<<<512, 256, 0, stream>>>(k0r, k0i, ws + OFF_KT0);
  k_init_kT<<<512, 256, 0, stream>>>(k1r, k1i, ws + OFF_KT1);
  k_dim<0><<<512, 256, 0, stream>>>(X, ws, out);   // writes out
  k_dim<1><<<512, 256, 0, stream>>>(X, ws, out);   // accumulates into out
}